// Round 4
// baseline (80.637 us; speedup 1.0000x reference)
//
#include <hip/hip_runtime.h>

// Fused single-kernel: 1x1-conv channel reduce + bilinear x4 (align_corners)
// + bias + ReLU. Channel reduction commutes with bilinear interp, so each
// block computes a reduced-image tile z in LDS, then upsamples from LDS.
//
// Round-4 fix: __builtin_nontemporal_store requires a clang ext_vector type,
// not HIP_vector_type<float,4> (compile error last round). Same codegen
// (global_store_dwordx4 nt) via f32x4 typedef.
//
// Kernel share of dur_us is ~8-10us; the rest is the harness's 256MiB
// workspace re-poison fill (~44us) + reset memsets sharing the timed stream.
//
// x: (4,64,96,320) f32 | weight: (1,64,1,1) | bias: (1,) | out: (4,1,384,1280)

typedef float f32x4 __attribute__((ext_vector_type(4)));

constexpr int C = 64, H = 96, W = 320, HW = H * W;
constexpr int Ho = 384, Wo = 1280;
constexpr int TOH = 16, TOW = 128;          // output tile per block
constexpr int NTR = Ho / TOH;               // 24
constexpr int NTC = Wo / TOW;               // 10
constexpr int NWG = 4 * NTR * NTC;          // 960 blocks (=8*120, XCD-bijective)
constexpr int ZR = 6, ZC = 40;              // staged reduced tile (rows span <=6,
                                            // cols span <=37, padded to 40)

__global__ __launch_bounds__(256)
void fused_kernel(const float* __restrict__ x,
                  const float* __restrict__ wgt,
                  const float* __restrict__ bias,
                  float* __restrict__ out)
{
    constexpr float RH = 95.0f / 383.0f;    // (H-1)/(Ho-1), f32 as in JAX
    constexpr float RW = 319.0f / 1279.0f;  // (W-1)/(Wo-1)

    __shared__ float zt[ZR][ZC];

    // XCD-aware swizzle (960 % 8 == 0 -> bijective): each XCD gets a
    // contiguous 120-tile chunk so shared halo rows stay in its private L2.
    int bid = blockIdx.x;
    bid = (bid & 7) * (NWG / 8) + (bid >> 3);

    const int tc = bid % NTC;
    const int t2 = bid / NTC;
    const int tr = t2 % NTR;
    const int b  = t2 / NTR;

    const int tid = threadIdx.x;
    const float bv = bias[0];               // issue early; hides under phase 1

    const int oh0  = tr * TOH;
    const int ow0  = tc * TOW;
    const int r_lo = min((int)((float)oh0 * RH), H - 2);  // first input row
    const int j_lo = min((int)((float)ow0 * RW), W - 2);  // first input col
    const int jb   = j_lo & ~3;                           // float4-aligned base

    // ---- phase 1: z[r][j] = sum_c w[c]*x[b,c,r_lo+r,jb+j] into LDS.
    // 60 groups of 4 lanes; lane lc accumulates channels [lc*16, lc*16+16)
    // of one float4, then a 2-step xor-shuffle folds the 4 channel-subsets.
    {
        const int g  = tid >> 2;
        const int lc = tid & 3;
        if (g < ZR * (ZC / 4)) {
            // per-lane weight slice, straight to registers (no LDS, no barrier)
            const float4* w4 = (const float4*)wgt + lc * 4;
            const float4 wa = w4[0], wb = w4[1], wc = w4[2], wd = w4[3];
            const float w[16] = { wa.x, wa.y, wa.z, wa.w,
                                  wb.x, wb.y, wb.z, wb.w,
                                  wc.x, wc.y, wc.z, wc.w,
                                  wd.x, wd.y, wd.z, wd.w };

            const int r  = g / (ZC / 4);
            const int jq = g - r * (ZC / 4);
            const int rr = min(r_lo + r, H - 1);      // clamped dup rows unread
            const int cj = min(jb + 4 * jq, W - 4);   // clamped dup cols unread
            const float* p = x + (size_t)b * C * HW + (size_t)rr * W + cj
                               + (size_t)(lc * 16) * HW;
            float4 acc = make_float4(0.f, 0.f, 0.f, 0.f);
            #pragma unroll
            for (int k = 0; k < 16; ++k) {
                const float4 v = *(const float4*)(p + (size_t)k * HW);
                acc.x += v.x * w[k]; acc.y += v.y * w[k];
                acc.z += v.z * w[k]; acc.w += v.w * w[k];
            }
            acc.x += __shfl_xor(acc.x, 1); acc.y += __shfl_xor(acc.y, 1);
            acc.z += __shfl_xor(acc.z, 1); acc.w += __shfl_xor(acc.w, 1);
            acc.x += __shfl_xor(acc.x, 2); acc.y += __shfl_xor(acc.y, 2);
            acc.z += __shfl_xor(acc.z, 2); acc.w += __shfl_xor(acc.w, 2);
            if (lc == 0) *(float4*)&zt[r][4 * jq] = acc;
        }
    }
    __syncthreads();

    // ---- phase 2: upsample 16 rows x 32 float4 from LDS.
    // Half-wave (32 lanes) covers one full tile row -> 512 B store segments.
    // LDS reads: lane fq hits z index ~fq (stride-1 across lanes) -> no
    // bank conflicts (verified: SQ_LDS_BANK_CONFLICT == 0).
    const int fq = tid & 31;       // float4 index within tile row
    const int rb = tid >> 5;       // 0..7
    #pragma unroll
    for (int u = 0; u < 2; ++u) {
        const int   row = rb + 8 * u;
        const int   oh  = oh0 + row;
        const float phh = (float)oh * RH;
        const int   i0  = min((int)phh, H - 2);
        const float wy  = phh - (float)i0;
        const float* za = zt[i0 - r_lo];
        const float* zb = zt[i0 - r_lo + 1];
        float vals[4];
        #pragma unroll
        for (int j = 0; j < 4; ++j) {
            const int   ow = ow0 + 4 * fq + j;
            const float pw = (float)ow * RW;
            const int   j0 = min((int)pw, W - 2);
            const float wx = pw - (float)j0;
            const int   L  = j0 - jb;                 // 0..36, fits ZC=40
            const float top = za[L] * (1.f - wx) + za[L + 1] * wx;
            const float bot = zb[L] * (1.f - wx) + zb[L + 1] * wx;
            const float v   = top * (1.f - wy) + bot * wy + bv;
            vals[j] = fmaxf(v, 0.f);
        }
        f32x4* dst = (f32x4*)(out + ((size_t)b * Ho + oh) * Wo + ow0) + fq;
        f32x4 sv = { vals[0], vals[1], vals[2], vals[3] };
        __builtin_nontemporal_store(sv, dst);
    }
}

extern "C" void kernel_launch(void* const* d_in, const int* in_sizes, int n_in,
                              void* d_out, int out_size, void* d_ws, size_t ws_size,
                              hipStream_t stream) {
    fused_kernel<<<dim3(NWG), 256, 0, stream>>>(
        (const float*)d_in[0], (const float*)d_in[1],
        (const float*)d_in[2], (float*)d_out);
}